// Round 1
// baseline (921.921 us; speedup 1.0000x reference)
//
#include <hip/hip_runtime.h>
#include <math.h>
#include <stdint.h>

#define NTOK 16384
#define KD   4096
#define EDIM 64
#define MT   64                  // tokens per block
#define KC   128                 // k per chunk
#define NC   (KD / KC)           // 32 chunks
#define XTS  65                  // transposed-x row stride (floats): conflict-free b32 reads
#define BUFF (KC * XTS)          // 8320 floats per buffer
#define LSTR 132                 // logits row stride for epilogue
#define SMEMF (2 * BUFF + 4 * XTS)

__global__ __launch_bounds__(512, 2)
void router_fused(const float* __restrict__ x,
                  const float* __restrict__ noise,
                  const float* __restrict__ Wr,
                  const float* __restrict__ br,
                  const float* __restrict__ Wn,
                  const float* __restrict__ bn,
                  float* __restrict__ out) {
    __shared__ float smem[SMEMF];
    const int tid  = threadIdx.x;
    const int t0   = blockIdx.x * MT;
    const int lane = tid & 63;

    // wave-uniform column group: waves 0..3 -> W_route cols, waves 4..7 -> W_noise cols.
    // readfirstlane forces uniformity so W loads scalarize to s_load (SGPR weights).
    const int wv = __builtin_amdgcn_readfirstlane(tid >> 6);
    const float* __restrict__ Wsel = (wv < 4) ? Wr : Wn;
    const int c0 = (wv & 3) * 16;

    // staging roles: 512 threads load a 64-token x 128-k x-chunk, transposed into LDS
    const int sc = (tid & 31) * 4;     // k offset within chunk (0..124), coalesced float4
    const int sr = tid >> 5;           // token row within 16-row pass (0..15)
    const float* xsrc = x + (size_t)(t0 + sr) * KD + sc;

    float acc[16];
#pragma unroll
    for (int j = 0; j < 16; ++j) acc[j] = 0.f;

    // ---- prologue: chunk 0 -> buf0 ----
    float4 pf0 = *(const float4*)(xsrc);
    float4 pf1 = *(const float4*)(xsrc + (size_t)16 * KD);
    float4 pf2 = *(const float4*)(xsrc + (size_t)32 * KD);
    float4 pf3 = *(const float4*)(xsrc + (size_t)48 * KD);
    {
        float* d = smem;
#pragma unroll
        for (int i = 0; i < 4; ++i) {
            d[(sc + i) * XTS + sr     ] = (&pf0.x)[i];
            d[(sc + i) * XTS + sr + 16] = (&pf1.x)[i];
            d[(sc + i) * XTS + sr + 32] = (&pf2.x)[i];
            d[(sc + i) * XTS + sr + 48] = (&pf3.x)[i];
        }
    }

#define FMA16(xc, u0, u1, u2, u3) do { \
        acc[ 0] = fmaf(xc, u0.x, acc[ 0]); \
        acc[ 1] = fmaf(xc, u0.y, acc[ 1]); \
        acc[ 2] = fmaf(xc, u0.z, acc[ 2]); \
        acc[ 3] = fmaf(xc, u0.w, acc[ 3]); \
        acc[ 4] = fmaf(xc, u1.x, acc[ 4]); \
        acc[ 5] = fmaf(xc, u1.y, acc[ 5]); \
        acc[ 6] = fmaf(xc, u1.z, acc[ 6]); \
        acc[ 7] = fmaf(xc, u1.w, acc[ 7]); \
        acc[ 8] = fmaf(xc, u2.x, acc[ 8]); \
        acc[ 9] = fmaf(xc, u2.y, acc[ 9]); \
        acc[10] = fmaf(xc, u2.z, acc[10]); \
        acc[11] = fmaf(xc, u2.w, acc[11]); \
        acc[12] = fmaf(xc, u3.x, acc[12]); \
        acc[13] = fmaf(xc, u3.y, acc[13]); \
        acc[14] = fmaf(xc, u3.z, acc[14]); \
        acc[15] = fmaf(xc, u3.w, acc[15]); \
    } while (0)

    for (int c = 0; c < NC; ++c) {
        __syncthreads();                       // buf[c&1] ready for all waves
        const bool pre = (c + 1) < NC;
        if (pre) {                              // issue next-chunk global loads early
            const float* xs = xsrc + (size_t)(c + 1) * KC;
            pf0 = *(const float4*)(xs);
            pf1 = *(const float4*)(xs + (size_t)16 * KD);
            pf2 = *(const float4*)(xs + (size_t)32 * KD);
            pf3 = *(const float4*)(xs + (size_t)48 * KD);
        }

        const float* xt  = smem + (c & 1) * BUFF + lane;          // xT[k][lane]
        const float* wr_ = Wsel + c0 + (size_t)c * KC * EDIM;     // wave-uniform

        // 2-row software pipeline: scalar W loads + LDS x loads ahead of FMAs
        float4 wa0 = *(const float4*)(wr_ + 0);
        float4 wa1 = *(const float4*)(wr_ + 4);
        float4 wa2 = *(const float4*)(wr_ + 8);
        float4 wa3 = *(const float4*)(wr_ + 12);
        float4 wb0 = *(const float4*)(wr_ + EDIM + 0);
        float4 wb1 = *(const float4*)(wr_ + EDIM + 4);
        float4 wb2 = *(const float4*)(wr_ + EDIM + 8);
        float4 wb3 = *(const float4*)(wr_ + EDIM + 12);
        float xa = xt[0];
        float xb = xt[XTS];

#pragma unroll 2
        for (int kk = 0; kk < KC; kk += 2) {
            const float  xca = xa;
            const float4 ua0 = wa0, ua1 = wa1, ua2 = wa2, ua3 = wa3;
            if (kk + 2 < KC) {
                const float* nw = wr_ + (size_t)(kk + 2) * EDIM;
                wa0 = *(const float4*)(nw + 0);
                wa1 = *(const float4*)(nw + 4);
                wa2 = *(const float4*)(nw + 8);
                wa3 = *(const float4*)(nw + 12);
                xa  = xt[(kk + 2) * XTS];
            }
            FMA16(xca, ua0, ua1, ua2, ua3);

            const float  xcb = xb;
            const float4 ub0 = wb0, ub1 = wb1, ub2 = wb2, ub3 = wb3;
            if (kk + 3 < KC) {
                const float* nw = wr_ + (size_t)(kk + 3) * EDIM;
                wb0 = *(const float4*)(nw + 0);
                wb1 = *(const float4*)(nw + 4);
                wb2 = *(const float4*)(nw + 8);
                wb3 = *(const float4*)(nw + 12);
                xb  = xt[(kk + 3) * XTS];
            }
            FMA16(xcb, ub0, ub1, ub2, ub3);
        }

        if (pre) {                              // write next chunk to the other buffer
            float* d = smem + ((c + 1) & 1) * BUFF;
#pragma unroll
            for (int i = 0; i < 4; ++i) {
                d[(sc + i) * XTS + sr     ] = (&pf0.x)[i];
                d[(sc + i) * XTS + sr + 16] = (&pf1.x)[i];
                d[(sc + i) * XTS + sr + 32] = (&pf2.x)[i];
                d[(sc + i) * XTS + sr + 48] = (&pf3.x)[i];
            }
        }
    }

    // ---- logits -> LDS [64 tokens][132]: cols 0..63 route, 64..127 noise ----
    __syncthreads();   // all compute reads of LDS done before overwrite
#pragma unroll
    for (int q = 0; q < 4; ++q) {
        float4 v = make_float4(acc[q * 4 + 0], acc[q * 4 + 1],
                               acc[q * 4 + 2], acc[q * 4 + 3]);
        *(float4*)&smem[lane * LSTR + wv * 16 + q * 4] = v;
    }
    __syncthreads();

    // ---- epilogue: wave per token, lane = expert (unchanged numerics) ----
    const int wvid = tid >> 6;
    const float brl = br[lane], bnl = bn[lane];
    for (int it = 0; it < 8; ++it) {
        const int tl = wvid * 8 + it;
        const int tg = t0 + tl;
        float v  = smem[tl * LSTR + lane] + brl;
        float nz = smem[tl * LSTR + 64 + lane] + bnl;
        float sp = log1pf(expf(-fabsf(nz))) + fmaxf(nz, 0.f);   // stable softplus
        v += noise[(size_t)tg * EDIM + lane] * sp;

        float mx = v;
#pragma unroll
        for (int o = 32; o >= 1; o >>= 1) mx = fmaxf(mx, __shfl_xor(mx, o, 64));
        float p = expf(v - mx);
        float sm = p;
#pragma unroll
        for (int o = 32; o >= 1; o >>= 1) sm += __shfl_xor(sm, o, 64);
        float prob = p / sm;
        out[(size_t)NTOK * 16 + (size_t)tg * EDIM + lane] = prob;   // output 2

        float pv = prob;
        float wvals[8]; int widx[8]; float tsum = 0.f;
#pragma unroll
        for (int j = 0; j < 8; ++j) {
            float bv = pv; int bi = lane;
#pragma unroll
            for (int o = 32; o >= 1; o >>= 1) {
                float ov = __shfl_xor(bv, o, 64);
                int   oi = __shfl_xor(bi, o, 64);
                if (ov > bv || (ov == bv && oi < bi)) { bv = ov; bi = oi; }
            }
            wvals[j] = bv; widx[j] = bi; tsum += bv;
            if (lane == bi) pv = -1.0f;
        }
        if (lane < 8) {
            float myw = wvals[0]; int myi = widx[0];
#pragma unroll
            for (int j = 1; j < 8; ++j) if (lane == j) { myw = wvals[j]; myi = widx[j]; }
            out[(size_t)tg * 8 + lane] = myw / tsum;                       // output 0
            out[(size_t)NTOK * 8 + (size_t)tg * 8 + lane] = (float)myi;    // output 1
        }
    }
}

extern "C" void kernel_launch(void* const* d_in, const int* in_sizes, int n_in,
                              void* d_out, int out_size, void* d_ws, size_t ws_size,
                              hipStream_t stream) {
    const float* x     = (const float*)d_in[0];
    const float* noise = (const float*)d_in[1];
    const float* Wr    = (const float*)d_in[2];
    const float* br    = (const float*)d_in[3];
    const float* Wn    = (const float*)d_in[4];
    const float* bn    = (const float*)d_in[5];
    float* out = (float*)d_out;
    hipLaunchKernelGGL(router_fused, dim3(NTOK / MT), dim3(512), 0, stream,
                       x, noise, Wr, br, Wn, bn, out);
}

// Round 2
// 736.527 us; speedup vs baseline: 1.2517x; 1.2517x over previous
//
#include <hip/hip_runtime.h>
#include <math.h>
#include <stdint.h>

#define NTOK 16384
#define KD   4096
#define EDIM 64
#define MT   64                  // tokens per block
#define KC   128                 // k per chunk
#define NC   (KD / KC)           // 32 chunks
#define BUFF (MT * KC)           // 8192 floats per buffer
#define LSTR 132                 // logits row stride for epilogue

// acc row i gets x-value per kp (xv components) times W row kp (w components = 4 cols)
#define FMAG(xv, w0, w1, w2, w3, a) do {                          \
        a[0] = fmaf(xv.x, w0.x, a[0]);                            \
        a[0] = fmaf(xv.y, w1.x, a[0]);                            \
        a[0] = fmaf(xv.z, w2.x, a[0]);                            \
        a[0] = fmaf(xv.w, w3.x, a[0]);                            \
        a[1] = fmaf(xv.x, w0.y, a[1]);                            \
        a[1] = fmaf(xv.y, w1.y, a[1]);                            \
        a[1] = fmaf(xv.z, w2.y, a[1]);                            \
        a[1] = fmaf(xv.w, w3.y, a[1]);                            \
        a[2] = fmaf(xv.x, w0.z, a[2]);                            \
        a[2] = fmaf(xv.y, w1.z, a[2]);                            \
        a[2] = fmaf(xv.z, w2.z, a[2]);                            \
        a[2] = fmaf(xv.w, w3.z, a[2]);                            \
        a[3] = fmaf(xv.x, w0.w, a[3]);                            \
        a[3] = fmaf(xv.y, w1.w, a[3]);                            \
        a[3] = fmaf(xv.z, w2.w, a[3]);                            \
        a[3] = fmaf(xv.w, w3.w, a[3]);                            \
    } while (0)

__global__ __launch_bounds__(512, 2)
void router_fused(const float* __restrict__ x,
                  const float* __restrict__ noise,
                  const float* __restrict__ Wr,
                  const float* __restrict__ br,
                  const float* __restrict__ Wn,
                  const float* __restrict__ bn,
                  float* __restrict__ out) {
    __shared__ float smem[2 * BUFF];        // 64 KB: x double buffer, reused for logits
    const int tid  = threadIdx.x;
    const int t0   = blockIdx.x * MT;
    const int lane = tid & 63;
    const int wv   = tid >> 6;              // wave 0..7
    const int tg   = (tid >> 2) & 15;       // token group: tokens 4*tg..4*tg+3
    const int cg   = tid & 3;               // col group within wave's 16 cols
    const int sw   = tg & 7;                // x read swizzle key

    // wave -> 16 cols of Wr (waves 0-3) or Wn (waves 4-7); thread -> 4 cols (per-lane => vector VMEM)
    const float* __restrict__ Wsel = (wv < 4) ? Wr : Wn;
    const float* wbase = Wsel + ((wv & 3) * 16 + cg * 4);

    // staging roles: thread -> token row, 16 consecutive k (4 float4), coalesced global
    const int srow = tid >> 3;              // 0..63
    const int skq  = (tid & 7) * 16;        // float offset in k within chunk
    const int sc0  = skq >> 2;              // logical 16B-chunk index base
    const int ssw  = (srow >> 2) & 7;       // write-side swizzle key (must match read: row>>2)
    const float* xsrc = x + (size_t)(t0 + srow) * KD + skq;

    float acc[4][4];
#pragma unroll
    for (int i = 0; i < 4; ++i)
#pragma unroll
        for (int j = 0; j < 4; ++j) acc[i][j] = 0.f;

    // ---- prologue: stage x chunk 0 (swizzled: 16B-chunk c stored at c ^ ((row>>2)&7)) ----
    {
        float4 s0 = *(const float4*)(xsrc);
        float4 s1 = *(const float4*)(xsrc + 4);
        float4 s2 = *(const float4*)(xsrc + 8);
        float4 s3 = *(const float4*)(xsrc + 12);
        float* d = &smem[srow * KC];
        *(float4*)&d[((sc0 + 0) ^ ssw) << 2] = s0;
        *(float4*)&d[((sc0 + 1) ^ ssw) << 2] = s1;
        *(float4*)&d[((sc0 + 2) ^ ssw) << 2] = s2;
        *(float4*)&d[((sc0 + 3) ^ ssw) << 2] = s3;
    }

    // ---- W register pipeline: group = 4 k-rows; preload groups 0,1; rolling prefetch +2 ----
    const float* wlim = wbase + (size_t)1022 * 256;   // so pB (= +256) tops out at group 1023
    const float* wpre = wbase + 512;                  // next group to load = 2
    float4 wA0 = *(const float4*)(wbase +   0);
    float4 wA1 = *(const float4*)(wbase +  64);
    float4 wA2 = *(const float4*)(wbase + 128);
    float4 wA3 = *(const float4*)(wbase + 192);
    float4 wB0 = *(const float4*)(wbase + 256);
    float4 wB1 = *(const float4*)(wbase + 320);
    float4 wB2 = *(const float4*)(wbase + 384);
    float4 wB3 = *(const float4*)(wbase + 448);

    float4 s0, s1, s2, s3;
    for (int c = 0; c < NC; ++c) {
        __syncthreads();                              // x buf[c&1] ready
        const bool pre = (c + 1) < NC;
        if (pre) {                                    // issue next x chunk loads early
            const float* xs = xsrc + (size_t)(c + 1) * KC;
            s0 = *(const float4*)(xs);
            s1 = *(const float4*)(xs + 4);
            s2 = *(const float4*)(xs + 8);
            s3 = *(const float4*)(xs + 12);
        }

        const char* xrb = (const char*)&smem[(c & 1) * BUFF + (tg << 2) * KC];

        for (int gp = 0; gp < 16; ++gp) {             // 2 groups (8 k) per iteration
            const int g = gp << 1;
            const float* pA = wpre;
            const float* pB = wpre + 256;
            wpre += 512;
            if (wpre > wlim) wpre = wlim;             // clamp (tail reloads last rows, unused)

            // x reads for both groups: conflict-free via XOR swizzle, rows via imm offsets
            const int offA = ((g ^ sw) << 4);
            const int offB = (((g + 1) ^ sw) << 4);
            float4 xa0 = *(const float4*)(xrb + offA);
            float4 xa1 = *(const float4*)(xrb + offA + 512);
            float4 xa2 = *(const float4*)(xrb + offA + 1024);
            float4 xa3 = *(const float4*)(xrb + offA + 1536);
            float4 xb0 = *(const float4*)(xrb + offB);
            float4 xb1 = *(const float4*)(xrb + offB + 512);
            float4 xb2 = *(const float4*)(xrb + offB + 1024);
            float4 xb3 = *(const float4*)(xrb + offB + 1536);

            // consume group A (k = base+g*4 .. +3), then refill A from pA (used next iter)
            FMAG(xa0, wA0, wA1, wA2, wA3, acc[0]);
            FMAG(xa1, wA0, wA1, wA2, wA3, acc[1]);
            FMAG(xa2, wA0, wA1, wA2, wA3, acc[2]);
            FMAG(xa3, wA0, wA1, wA2, wA3, acc[3]);
            wA0 = *(const float4*)(pA);
            wA1 = *(const float4*)(pA + 64);
            wA2 = *(const float4*)(pA + 128);
            wA3 = *(const float4*)(pA + 192);

            // consume group B, refill B from pB
            FMAG(xb0, wB0, wB1, wB2, wB3, acc[0]);
            FMAG(xb1, wB0, wB1, wB2, wB3, acc[1]);
            FMAG(xb2, wB0, wB1, wB2, wB3, acc[2]);
            FMAG(xb3, wB0, wB1, wB2, wB3, acc[3]);
            wB0 = *(const float4*)(pB);
            wB1 = *(const float4*)(pB + 64);
            wB2 = *(const float4*)(pB + 128);
            wB3 = *(const float4*)(pB + 192);
        }

        if (pre) {                                    // write staged x to the other buffer
            float* d = &smem[((c + 1) & 1) * BUFF + srow * KC];
            *(float4*)&d[((sc0 + 0) ^ ssw) << 2] = s0;
            *(float4*)&d[((sc0 + 1) ^ ssw) << 2] = s1;
            *(float4*)&d[((sc0 + 2) ^ ssw) << 2] = s2;
            *(float4*)&d[((sc0 + 3) ^ ssw) << 2] = s3;
        }
    }

    // ---- logits -> LDS [64 tokens][132]: cols 0..63 route, 64..127 noise ----
    __syncthreads();   // all LDS x reads done before overwrite
    {
        const int colbase = ((wv & 4) << 4) + ((wv & 3) << 4) + (cg << 2);
#pragma unroll
        for (int i = 0; i < 4; ++i) {
            float4 v = make_float4(acc[i][0], acc[i][1], acc[i][2], acc[i][3]);
            *(float4*)&smem[((tg << 2) + i) * LSTR + colbase] = v;
        }
    }
    __syncthreads();

    // ---- epilogue: wave per token, lane = expert (numerics unchanged) ----
    const int wvid = tid >> 6;
    const float brl = br[lane], bnl = bn[lane];
    for (int it = 0; it < 8; ++it) {
        const int tl = wvid * 8 + it;
        const int tg_ = t0 + tl;
        float v  = smem[tl * LSTR + lane] + brl;
        float nz = smem[tl * LSTR + 64 + lane] + bnl;
        float sp = log1pf(expf(-fabsf(nz))) + fmaxf(nz, 0.f);   // stable softplus
        v += noise[(size_t)tg_ * EDIM + lane] * sp;

        float mx = v;
#pragma unroll
        for (int o = 32; o >= 1; o >>= 1) mx = fmaxf(mx, __shfl_xor(mx, o, 64));
        float p = expf(v - mx);
        float sm = p;
#pragma unroll
        for (int o = 32; o >= 1; o >>= 1) sm += __shfl_xor(sm, o, 64);
        float prob = p / sm;
        out[(size_t)NTOK * 16 + (size_t)tg_ * EDIM + lane] = prob;   // output 2

        float pv = prob;
        float wvals[8]; int widx[8]; float tsum = 0.f;
#pragma unroll
        for (int j = 0; j < 8; ++j) {
            float bv = pv; int bi = lane;
#pragma unroll
            for (int o = 32; o >= 1; o >>= 1) {
                float ov = __shfl_xor(bv, o, 64);
                int   oi = __shfl_xor(bi, o, 64);
                if (ov > bv || (ov == bv && oi < bi)) { bv = ov; bi = oi; }
            }
            wvals[j] = bv; widx[j] = bi; tsum += bv;
            if (lane == bi) pv = -1.0f;
        }
        if (lane < 8) {
            float myw = wvals[0]; int myi = widx[0];
#pragma unroll
            for (int j = 1; j < 8; ++j) if (lane == j) { myw = wvals[j]; myi = widx[j]; }
            out[(size_t)tg_ * 8 + lane] = myw / tsum;                       // output 0
            out[(size_t)NTOK * 8 + (size_t)tg_ * 8 + lane] = (float)myi;    // output 1
        }
    }
}

extern "C" void kernel_launch(void* const* d_in, const int* in_sizes, int n_in,
                              void* d_out, int out_size, void* d_ws, size_t ws_size,
                              hipStream_t stream) {
    const float* x     = (const float*)d_in[0];
    const float* noise = (const float*)d_in[1];
    const float* Wr    = (const float*)d_in[2];
    const float* br    = (const float*)d_in[3];
    const float* Wn    = (const float*)d_in[4];
    const float* bn    = (const float*)d_in[5];
    float* out = (float*)d_out;
    hipLaunchKernelGGL(router_fused, dim3(NTOK / MT), dim3(512), 0, stream,
                       x, noise, Wr, br, Wn, bn, out);
}